// Round 1
// baseline (628.971 us; speedup 1.0000x reference)
//
#include <hip/hip_runtime.h>
#include <stdint.h>

// B=4, S=2048, D=1024, H=16, Hd=64, M=8192.
// Pipeline: cast x -> bf16; merged W^T casts; merged QKV GEMM (Q pre-scaled
// by log2e/8); V transpose to [bh][hd][s]; flash attn computing S^T = K@Q^T
// so exp2(scores) form PV A-frags in-register (key-permutation trick, no P
// LDS round-trip); O-projection GEMM (fp32 out).
// R1: attn occupancy fix — 1024 blocks (128 q-rows, 32 q/wave), 4 waves/SIMD,
// XCD-grouped head decode, setprio around MFMA clusters.

typedef float f32x4 __attribute__((ext_vector_type(4)));
typedef __bf16 bf16x4 __attribute__((ext_vector_type(4)));
typedef __bf16 bf16x8 __attribute__((ext_vector_type(8)));
typedef uint32_t u32x4 __attribute__((ext_vector_type(4)));

#define MFMA16(a, b, c) __builtin_amdgcn_mfma_f32_16x16x32_bf16((a), (b), (c), 0, 0, 0)

// Q pre-scale: log2(e)/8 so attn does p = exp2(Q'.K) = e^{QK/8} (unnormalized)
#define QSCALE 0.1803368801111204f

__device__ __forceinline__ unsigned short f2bf(float f) {
  union { float f; uint32_t u; } c; c.f = f;
  uint32_t u = c.u;
  return (unsigned short)((u + 0x7fffu + ((u >> 16) & 1u)) >> 16);  // RNE
}

// ---------------------------------------------------------------- casts
__global__ __launch_bounds__(256) void cast_x_kernel(const float* __restrict__ in,
                                                     unsigned short* __restrict__ out,
                                                     int n4) {
  int i = blockIdx.x * 256 + threadIdx.x;
  if (i >= n4) return;
  float4 v = ((const float4*)in)[i];
  ushort4 o;
  o.x = f2bf(v.x); o.y = f2bf(v.y); o.z = f2bf(v.z); o.w = f2bf(v.w);
  ((ushort4*)out)[i] = o;
}

// 4 weights [k][n] fp32 -> Wt [n][k] bf16, z selects matrix; dst contiguous.
__global__ __launch_bounds__(256) void transpose_cast4(const float* __restrict__ W0,
                                                       const float* __restrict__ W1,
                                                       const float* __restrict__ W2,
                                                       const float* __restrict__ W3,
                                                       unsigned short* __restrict__ Wt) {
  __shared__ float tile[32][33];
  const int z = blockIdx.z;
  const float* W = (z == 0) ? W0 : (z == 1) ? W1 : (z == 2) ? W2 : W3;
  unsigned short* dst = Wt + (size_t)z * 1048576;
  int k0 = blockIdx.x * 32, n0 = blockIdx.y * 32;
  int tx = threadIdx.x, ty = threadIdx.y;
#pragma unroll
  for (int i = 0; i < 32; i += 8)
    tile[ty + i][tx] = W[(size_t)(k0 + ty + i) * 1024 + n0 + tx];
  __syncthreads();
#pragma unroll
  for (int i = 0; i < 32; i += 8)
    dst[(size_t)(n0 + ty + i) * 1024 + k0 + tx] = f2bf(tile[tx][ty + i]);
}

// ---------------------------------------------------------------- GEMM
// MODE 0: O-proj. out fp32 [8192][1024], bias b0.
// MODE 1: merged QKV. Bt = [3072][1024], out = QKV bf16 base (3 x 8388608),
//         scatter to [b,h,s,hd]; Q (mb==0) scaled by QSCALE. biases b0,b1,b2.
template <int MODE>
__global__ __launch_bounds__(256) void gemm128(const unsigned short* __restrict__ A,
                                               const unsigned short* __restrict__ Bt,
                                               const float* __restrict__ b0,
                                               const float* __restrict__ b1,
                                               const float* __restrict__ b2,
                                               void* __restrict__ out) {
  constexpr int Kd = 1024;
  __shared__ unsigned short sm[128 * 32 + 32 * 128];
  unsigned short* As = sm;
  unsigned short* Bs = sm + 128 * 32;
  auto lds3 = (__attribute__((address_space(3))) char*)sm;

  const int tid = threadIdx.x;
  const int wave = tid >> 6, lane = tid & 63, quad = lane >> 4, l16 = lane & 15;
  const int wm = wave >> 1, wn = wave & 1;
  const int bm = blockIdx.y * 128, bn = blockIdx.x * 128;

  f32x4 acc[4][4] = {};

  for (int k0 = 0; k0 < Kd; k0 += 32) {
#pragma unroll
    for (int j = 0; j < 2; ++j) {
      int i = (wave * 2 + j) * 64 + lane;  // 16B-chunk index 0..511
      const unsigned short* ga = A + (size_t)(bm + (i >> 2)) * Kd + k0 + (i & 3) * 8;
      __builtin_amdgcn_global_load_lds(
          (const __attribute__((address_space(1))) void*)ga,
          (__attribute__((address_space(3))) void*)(lds3 + (size_t)(wave * 2 + j) * 1024),
          16, 0, 0);
      const unsigned short* gb = Bt + (size_t)(bn + (i >> 2)) * Kd + k0 + (i & 3) * 8;
      __builtin_amdgcn_global_load_lds(
          (const __attribute__((address_space(1))) void*)gb,
          (__attribute__((address_space(3))) void*)(lds3 + 8192 + (size_t)(wave * 2 + j) * 1024),
          16, 0, 0);
    }
    __syncthreads();

    bf16x8 af[4], bfv[4];
#pragma unroll
    for (int i = 0; i < 4; ++i)
      af[i] = *(const bf16x8*)(As + (wm * 64 + i * 16 + l16) * 32 + quad * 8);
#pragma unroll
    for (int n = 0; n < 4; ++n)
      bfv[n] = *(const bf16x8*)(Bs + (wn * 64 + n * 16 + l16) * 32 + quad * 8);
#pragma unroll
    for (int i = 0; i < 4; ++i)
#pragma unroll
      for (int n = 0; n < 4; ++n)
        acc[i][n] = MFMA16(af[i], bfv[n], acc[i][n]);
    __syncthreads();
  }

  // epilogue: C/D layout col=lane&15, row=quad*4+reg
  const int mb = bn >> 10;  // matrix id for MODE 1 (block never straddles: 1024%128==0)
  const float* bias = (MODE == 0) ? b0 : (mb == 0 ? b0 : (mb == 1 ? b1 : b2));
  const float scale = (MODE == 1 && mb == 0) ? QSCALE : 1.0f;
  unsigned short* oq = (MODE == 1) ? ((unsigned short*)out + (size_t)mb * 8388608u) : nullptr;

#pragma unroll
  for (int i = 0; i < 4; ++i) {
    const int row0 = bm + wm * 64 + i * 16 + quad * 4;
#pragma unroll
    for (int n = 0; n < 4; ++n) {
      const int col = bn + wn * 64 + n * 16 + l16;
      const int cl = col & 1023;
      const float bv = bias[cl];
#pragma unroll
      for (int r = 0; r < 4; ++r) {
        float v = (acc[i][n][r] + bv) * scale;
        if (MODE == 0) {
          ((float*)out)[(size_t)(row0 + r) * 1024 + col] = v;
        } else {
          int rr = row0 + r;
          int b = rr >> 11, s = rr & 2047;
          int h = cl >> 6, hd = cl & 63;
          oq[((size_t)(b * 16 + h) * 2048 + s) * 64 + hd] = f2bf(v);
        }
      }
    }
  }
}

// ---------------------------------------------------------------- V transpose
// Vb [bh][s][64] bf16 -> VtG [bh][64][2048] bf16.
__global__ __launch_bounds__(256) void transpose_v(const unsigned short* __restrict__ Vb,
                                                   unsigned short* __restrict__ VtG) {
  __shared__ uint32_t t32[64][33];
  const int bh = blockIdx.y, s0 = blockIdx.x * 64;
  const int tid = threadIdx.x;
  const size_t hbase = (size_t)bh * 131072;
#pragma unroll
  for (int it = 0; it < 2; ++it) {
    int c = tid + it * 256;
    int sr = c >> 3, o4 = (c & 7) * 4;
    u32x4 v = *(const u32x4*)(Vb + hbase + (size_t)(s0 + sr) * 64 + o4 * 2);
    t32[sr][o4] = v[0]; t32[sr][o4 + 1] = v[1];
    t32[sr][o4 + 2] = v[2]; t32[sr][o4 + 3] = v[3];
  }
  __syncthreads();
#pragma unroll
  for (int it = 0; it < 2; ++it) {
    int c = tid + it * 256;
    int hd = c >> 3, so = (c & 7) * 8;
    int hc = hd >> 1, sh = (hd & 1) * 16;
    uint32_t w[4];
#pragma unroll
    for (int j = 0; j < 4; ++j) {
      uint32_t lo = t32[so + 2 * j][hc], hi = t32[so + 2 * j + 1][hc];
      w[j] = ((lo >> sh) & 0xffffu) | (((hi >> sh) & 0xffffu) << 16);
    }
    *(u32x4*)(VtG + hbase + (size_t)hd * 2048 + s0 + so) = *(u32x4*)w;
  }
}

// ---------------------------------------------------------------- flash attention
// Q pre-scaled. 1024 blocks; block = (b,h) x 128 q-rows; wave = 32 q-rows
// (2 subtiles). XCD-grouped decode: bh = (id&7)*8 + (id>>3)/16 so all 16
// q-blocks of a head (and 8 whole heads) land on one XCD -> K/Vt L2-resident.
// S^T = K(A) @ Q^T(B): C-layout puts col=l16=qrow, so each lane's 16 exp2'd
// scores (keys quad*4+r per subtile) form PV A-frags directly under the key
// permutation sigma(q*8+j) = st*32 + (j>>2)*16 + q*4 + (j&3); V B-frags use
// the same sigma (two contiguous b64 chunks from the Vt tile). No P in LDS.
__global__ __launch_bounds__(256, 4) void attn_kernel(const unsigned short* __restrict__ Q,
                                                      const unsigned short* __restrict__ K,
                                                      const unsigned short* __restrict__ Vt,
                                                      unsigned short* __restrict__ ctx) {
  const int tid = threadIdx.x;
  const int wave = tid >> 6, lane = tid & 63, quad = lane >> 4, l16 = lane & 15;

  const int id = blockIdx.x;
  const int bh = (id & 7) * 8 + ((id >> 3) >> 4);  // 8 heads per XCD
  const int qx = (id >> 3) & 15;

  // stride 72 ushorts = 36 dwords == 4 mod 32 -> conflict-free-ish frag reads
  // double buffer: [buf][Ks 64*72 | Vts 64*72]
  __shared__ unsigned short sm[2][2 * 64 * 72];

  const size_t hb = (size_t)bh * 131072;
  const int q0 = qx * 128 + wave * 32;

  // Q B-frags: B[k=hd][n=qrow]: lane l16 = qrow, k = quad*8+j (+32*st)
  bf16x8 qf[2][2];
#pragma unroll
  for (int qt = 0; qt < 2; ++qt)
#pragma unroll
    for (int st = 0; st < 2; ++st)
      qf[qt][st] = *(const bf16x8*)(Q + hb + (size_t)(q0 + qt * 16 + l16) * 64 + st * 32 + quad * 8);

  f32x4 o[2][4] = {};
  float lacc[2] = {0.f, 0.f};

  // staging: 4 x 16B chunks/thread (2 K rows-of-keys + 2 Vt rows-of-hd)
  const int c0 = tid, c1 = tid + 256;
  const unsigned short* gK0 = K + hb + (size_t)(c0 >> 3) * 64 + (c0 & 7) * 8;
  const unsigned short* gK1 = K + hb + (size_t)(c1 >> 3) * 64 + (c1 & 7) * 8;
  const unsigned short* gV0 = Vt + hb + (size_t)(c0 >> 3) * 2048 + (c0 & 7) * 8;
  const unsigned short* gV1 = Vt + hb + (size_t)(c1 >> 3) * 2048 + (c1 & 7) * 8;
  const int sKo = (c0 >> 3) * 72 + (c0 & 7) * 8;
  const int sKo1 = (c1 >> 3) * 72 + (c1 & 7) * 8;

  u32x4 pk0 = *(const u32x4*)gK0, pk1 = *(const u32x4*)gK1;
  u32x4 pv0 = *(const u32x4*)gV0, pv1 = *(const u32x4*)gV1;
  {
    unsigned short* s0b = sm[0];
    *(u32x4*)(s0b + sKo) = pk0; *(u32x4*)(s0b + sKo1) = pk1;
    *(u32x4*)(s0b + 4608 + sKo) = pv0; *(u32x4*)(s0b + 4608 + sKo1) = pv1;
  }
  __syncthreads();

  for (int kb = 0; kb < 2048; kb += 64) {
    const int cur = (kb >> 6) & 1;
    const bool more = (kb + 64) < 2048;
    if (more) {
      pk0 = *(const u32x4*)(gK0 + (size_t)(kb + 64) * 64);
      pk1 = *(const u32x4*)(gK1 + (size_t)(kb + 64) * 64);
      pv0 = *(const u32x4*)(gV0 + kb + 64);
      pv1 = *(const u32x4*)(gV1 + kb + 64);
    }
    const unsigned short* Ks = sm[cur];
    const unsigned short* Vts = sm[cur] + 4608;

    // K A-frags: A[m=key][k=hd]: lane l16 = key (per subtile ks), contiguous hd
    bf16x8 kf[4][2];
#pragma unroll
    for (int ks = 0; ks < 4; ++ks)
#pragma unroll
      for (int st = 0; st < 2; ++st)
        kf[ks][st] = *(const bf16x8*)(Ks + (ks * 16 + l16) * 72 + st * 32 + quad * 8);

    // V B-frags under sigma: two b64 chunks (keys st*32+quad*4+{0..3}, +16)
    bf16x8 vf[4][2];
#pragma unroll
    for (int os = 0; os < 4; ++os)
#pragma unroll
      for (int st = 0; st < 2; ++st) {
        const unsigned short* rb = Vts + (os * 16 + l16) * 72 + st * 32 + quad * 4;
        bf16x4 a = *(const bf16x4*)rb;
        bf16x4 b2 = *(const bf16x4*)(rb + 16);
        vf[os][st] = __builtin_shufflevector(a, b2, 0, 1, 2, 3, 4, 5, 6, 7);
      }

#pragma unroll
    for (int qt = 0; qt < 2; ++qt) {
      // S^T tiles: rows = keys (quad*4+r), cols = qrows (l16)
      f32x4 sc[4];
      __builtin_amdgcn_s_setprio(1);
#pragma unroll
      for (int ks = 0; ks < 4; ++ks) {
        f32x4 a = {0.f, 0.f, 0.f, 0.f};
        a = MFMA16(kf[ks][0], qf[qt][0], a);
        a = MFMA16(kf[ks][1], qf[qt][1], a);
        sc[ks] = a;
      }
      __builtin_amdgcn_s_setprio(0);
      // exp2 -> P A-frags in-register; per-lane l partials (all for qrow l16)
      bf16x8 pf[2];
      float ls = 0.f;
#pragma unroll
      for (int ks = 0; ks < 4; ++ks)
#pragma unroll
        for (int r = 0; r < 4; ++r) {
          float p = __builtin_amdgcn_exp2f(sc[ks][r]);
          ls += p;
          pf[ks >> 1][(ks & 1) * 4 + r] = (__bf16)p;
        }
      lacc[qt] += ls;
      __builtin_amdgcn_s_setprio(1);
#pragma unroll
      for (int st = 0; st < 2; ++st)
#pragma unroll
        for (int os = 0; os < 4; ++os)
          o[qt][os] = MFMA16(pf[st], vf[os][st], o[qt][os]);
      __builtin_amdgcn_s_setprio(0);
    }

    if (more) {
      unsigned short* sn = sm[cur ^ 1];
      *(u32x4*)(sn + sKo) = pk0; *(u32x4*)(sn + sKo1) = pk1;
      *(u32x4*)(sn + 4608 + sKo) = pv0; *(u32x4*)(sn + 4608 + sKo1) = pv1;
    }
    __syncthreads();
  }

  // finalize: reduce l across quads (lane's l16 = qrow), redistribute to
  // C-layout rows (quad*4+r), normalize, store.
  const int b = bh >> 4, h = bh & 15;
#pragma unroll
  for (int qt = 0; qt < 2; ++qt) {
    float l = lacc[qt];
    l += __shfl_xor(l, 16, 64);
    l += __shfl_xor(l, 32, 64);
#pragma unroll
    for (int r = 0; r < 4; ++r) {
      float lr = __shfl(l, quad * 4 + r, 16);
      float inv = 1.0f / lr;
      int s = q0 + qt * 16 + quad * 4 + r;
#pragma unroll
      for (int os = 0; os < 4; ++os)
        ctx[((size_t)(b * 2048 + s)) * 1024 + h * 64 + os * 16 + l16] = f2bf(o[qt][os][r] * inv);
    }
  }
}

// ---------------------------------------------------------------- launch
extern "C" void kernel_launch(void* const* d_in, const int* in_sizes, int n_in,
                              void* d_out, int out_size, void* d_ws, size_t ws_size,
                              hipStream_t stream) {
  const float* x  = (const float*)d_in[0];
  const float* Wq = (const float*)d_in[1];
  const float* bq = (const float*)d_in[2];
  const float* Wk = (const float*)d_in[3];
  const float* bk = (const float*)d_in[4];
  const float* Wv = (const float*)d_in[5];
  const float* bv = (const float*)d_in[6];
  const float* Wo = (const float*)d_in[7];
  const float* bo = (const float*)d_in[8];

  unsigned short* ws = (unsigned short*)d_ws;
  unsigned short* xb    = ws;                    // 8388608 (aliased by VtG later)
  unsigned short* Wtall = ws + 8388608;          // 4*1048576 (Wq^T|Wk^T|Wv^T|Wo^T)
  unsigned short* Wot   = Wtall + 3145728;
  unsigned short* Qb    = Wtall + 4194304;       // 8388608  [bh][s][hd], pre-scaled
  unsigned short* Kb    = Qb + 8388608;          // 8388608
  unsigned short* Vb    = Kb + 8388608;          // 8388608
  unsigned short* VtG   = xb;                    // alias: xb dead after QKV GEMM
  unsigned short* Cb    = Vb;                    // alias: Vb dead after transpose_v

  cast_x_kernel<<<8192, 256, 0, stream>>>(x, xb, 2097152);
  transpose_cast4<<<dim3(32, 32, 4), dim3(32, 8), 0, stream>>>(Wq, Wk, Wv, Wo, Wtall);

  gemm128<1><<<dim3(24, 64), 256, 0, stream>>>(xb, Wtall, bq, bk, bv, Qb);
  transpose_v<<<dim3(32, 64), 256, 0, stream>>>(Vb, VtG);
  attn_kernel<<<dim3(1024), 256, 0, stream>>>(Qb, Kb, VtG, Cb);
  gemm128<0><<<dim3(8, 64), 256, 0, stream>>>(Cb, Wot, bo, nullptr, nullptr, d_out);
}

// Round 2
// 293.266 us; speedup vs baseline: 2.1447x; 2.1447x over previous
//
#include <hip/hip_runtime.h>
#include <stdint.h>

// B=4, S=2048, D=1024, H=16, Hd=64, M=8192.
// Pipeline: cast x -> bf16; merged W^T casts; merged QKV GEMM (Q pre-scaled
// by log2e/8); V transpose to [bh][hd][s]; flash attn computing S^T = K@Q^T
// so exp2(scores) form PV A-frags in-register (key-permutation trick, no P
// LDS round-trip); O-projection GEMM (fp32 out).
// R1: attn occupancy fix — 1024 blocks (128 q-rows, 32 q/wave), 4 waves/SIMD,
// XCD-grouped head decode, setprio around MFMA clusters.
// R2: launch_bounds(256,4) -> (256,2). The (.,4) min-occupancy arg capped the
// allocator at 64 VGPR (< ~110 live set) -> scratch spills (1.4 GB WRITE_SIZE,
// MfmaUtil 6%). LDS (36.9KB) is the binding resource for 4 blocks/CU; no
// register coercion needed.

typedef float f32x4 __attribute__((ext_vector_type(4)));
typedef __bf16 bf16x4 __attribute__((ext_vector_type(4)));
typedef __bf16 bf16x8 __attribute__((ext_vector_type(8)));
typedef uint32_t u32x4 __attribute__((ext_vector_type(4)));

#define MFMA16(a, b, c) __builtin_amdgcn_mfma_f32_16x16x32_bf16((a), (b), (c), 0, 0, 0)

// Q pre-scale: log2(e)/8 so attn does p = exp2(Q'.K) = e^{QK/8} (unnormalized)
#define QSCALE 0.1803368801111204f

__device__ __forceinline__ unsigned short f2bf(float f) {
  union { float f; uint32_t u; } c; c.f = f;
  uint32_t u = c.u;
  return (unsigned short)((u + 0x7fffu + ((u >> 16) & 1u)) >> 16);  // RNE
}

// ---------------------------------------------------------------- casts
__global__ __launch_bounds__(256) void cast_x_kernel(const float* __restrict__ in,
                                                     unsigned short* __restrict__ out,
                                                     int n4) {
  int i = blockIdx.x * 256 + threadIdx.x;
  if (i >= n4) return;
  float4 v = ((const float4*)in)[i];
  ushort4 o;
  o.x = f2bf(v.x); o.y = f2bf(v.y); o.z = f2bf(v.z); o.w = f2bf(v.w);
  ((ushort4*)out)[i] = o;
}

// 4 weights [k][n] fp32 -> Wt [n][k] bf16, z selects matrix; dst contiguous.
__global__ __launch_bounds__(256) void transpose_cast4(const float* __restrict__ W0,
                                                       const float* __restrict__ W1,
                                                       const float* __restrict__ W2,
                                                       const float* __restrict__ W3,
                                                       unsigned short* __restrict__ Wt) {
  __shared__ float tile[32][33];
  const int z = blockIdx.z;
  const float* W = (z == 0) ? W0 : (z == 1) ? W1 : (z == 2) ? W2 : W3;
  unsigned short* dst = Wt + (size_t)z * 1048576;
  int k0 = blockIdx.x * 32, n0 = blockIdx.y * 32;
  int tx = threadIdx.x, ty = threadIdx.y;
#pragma unroll
  for (int i = 0; i < 32; i += 8)
    tile[ty + i][tx] = W[(size_t)(k0 + ty + i) * 1024 + n0 + tx];
  __syncthreads();
#pragma unroll
  for (int i = 0; i < 32; i += 8)
    dst[(size_t)(n0 + ty + i) * 1024 + k0 + tx] = f2bf(tile[tx][ty + i]);
}

// ---------------------------------------------------------------- GEMM
// MODE 0: O-proj. out fp32 [8192][1024], bias b0.
// MODE 1: merged QKV. Bt = [3072][1024], out = QKV bf16 base (3 x 8388608),
//         scatter to [b,h,s,hd]; Q (mb==0) scaled by QSCALE. biases b0,b1,b2.
template <int MODE>
__global__ __launch_bounds__(256) void gemm128(const unsigned short* __restrict__ A,
                                               const unsigned short* __restrict__ Bt,
                                               const float* __restrict__ b0,
                                               const float* __restrict__ b1,
                                               const float* __restrict__ b2,
                                               void* __restrict__ out) {
  constexpr int Kd = 1024;
  __shared__ unsigned short sm[128 * 32 + 32 * 128];
  unsigned short* As = sm;
  unsigned short* Bs = sm + 128 * 32;
  auto lds3 = (__attribute__((address_space(3))) char*)sm;

  const int tid = threadIdx.x;
  const int wave = tid >> 6, lane = tid & 63, quad = lane >> 4, l16 = lane & 15;
  const int wm = wave >> 1, wn = wave & 1;
  const int bm = blockIdx.y * 128, bn = blockIdx.x * 128;

  f32x4 acc[4][4] = {};

  for (int k0 = 0; k0 < Kd; k0 += 32) {
#pragma unroll
    for (int j = 0; j < 2; ++j) {
      int i = (wave * 2 + j) * 64 + lane;  // 16B-chunk index 0..511
      const unsigned short* ga = A + (size_t)(bm + (i >> 2)) * Kd + k0 + (i & 3) * 8;
      __builtin_amdgcn_global_load_lds(
          (const __attribute__((address_space(1))) void*)ga,
          (__attribute__((address_space(3))) void*)(lds3 + (size_t)(wave * 2 + j) * 1024),
          16, 0, 0);
      const unsigned short* gb = Bt + (size_t)(bn + (i >> 2)) * Kd + k0 + (i & 3) * 8;
      __builtin_amdgcn_global_load_lds(
          (const __attribute__((address_space(1))) void*)gb,
          (__attribute__((address_space(3))) void*)(lds3 + 8192 + (size_t)(wave * 2 + j) * 1024),
          16, 0, 0);
    }
    __syncthreads();

    bf16x8 af[4], bfv[4];
#pragma unroll
    for (int i = 0; i < 4; ++i)
      af[i] = *(const bf16x8*)(As + (wm * 64 + i * 16 + l16) * 32 + quad * 8);
#pragma unroll
    for (int n = 0; n < 4; ++n)
      bfv[n] = *(const bf16x8*)(Bs + (wn * 64 + n * 16 + l16) * 32 + quad * 8);
#pragma unroll
    for (int i = 0; i < 4; ++i)
#pragma unroll
      for (int n = 0; n < 4; ++n)
        acc[i][n] = MFMA16(af[i], bfv[n], acc[i][n]);
    __syncthreads();
  }

  // epilogue: C/D layout col=lane&15, row=quad*4+reg
  const int mb = bn >> 10;  // matrix id for MODE 1 (block never straddles: 1024%128==0)
  const float* bias = (MODE == 0) ? b0 : (mb == 0 ? b0 : (mb == 1 ? b1 : b2));
  const float scale = (MODE == 1 && mb == 0) ? QSCALE : 1.0f;
  unsigned short* oq = (MODE == 1) ? ((unsigned short*)out + (size_t)mb * 8388608u) : nullptr;

#pragma unroll
  for (int i = 0; i < 4; ++i) {
    const int row0 = bm + wm * 64 + i * 16 + quad * 4;
#pragma unroll
    for (int n = 0; n < 4; ++n) {
      const int col = bn + wn * 64 + n * 16 + l16;
      const int cl = col & 1023;
      const float bv = bias[cl];
#pragma unroll
      for (int r = 0; r < 4; ++r) {
        float v = (acc[i][n][r] + bv) * scale;
        if (MODE == 0) {
          ((float*)out)[(size_t)(row0 + r) * 1024 + col] = v;
        } else {
          int rr = row0 + r;
          int b = rr >> 11, s = rr & 2047;
          int h = cl >> 6, hd = cl & 63;
          oq[((size_t)(b * 16 + h) * 2048 + s) * 64 + hd] = f2bf(v);
        }
      }
    }
  }
}

// ---------------------------------------------------------------- V transpose
// Vb [bh][s][64] bf16 -> VtG [bh][64][2048] bf16.
__global__ __launch_bounds__(256) void transpose_v(const unsigned short* __restrict__ Vb,
                                                   unsigned short* __restrict__ VtG) {
  __shared__ uint32_t t32[64][33];
  const int bh = blockIdx.y, s0 = blockIdx.x * 64;
  const int tid = threadIdx.x;
  const size_t hbase = (size_t)bh * 131072;
#pragma unroll
  for (int it = 0; it < 2; ++it) {
    int c = tid + it * 256;
    int sr = c >> 3, o4 = (c & 7) * 4;
    u32x4 v = *(const u32x4*)(Vb + hbase + (size_t)(s0 + sr) * 64 + o4 * 2);
    t32[sr][o4] = v[0]; t32[sr][o4 + 1] = v[1];
    t32[sr][o4 + 2] = v[2]; t32[sr][o4 + 3] = v[3];
  }
  __syncthreads();
#pragma unroll
  for (int it = 0; it < 2; ++it) {
    int c = tid + it * 256;
    int hd = c >> 3, so = (c & 7) * 8;
    int hc = hd >> 1, sh = (hd & 1) * 16;
    uint32_t w[4];
#pragma unroll
    for (int j = 0; j < 4; ++j) {
      uint32_t lo = t32[so + 2 * j][hc], hi = t32[so + 2 * j + 1][hc];
      w[j] = ((lo >> sh) & 0xffffu) | (((hi >> sh) & 0xffffu) << 16);
    }
    *(u32x4*)(VtG + hbase + (size_t)hd * 2048 + s0 + so) = *(u32x4*)w;
  }
}

// ---------------------------------------------------------------- flash attention
// Q pre-scaled. 1024 blocks; block = (b,h) x 128 q-rows; wave = 32 q-rows
// (2 subtiles). XCD-grouped decode: bh = (id&7)*8 + (id>>3)/16 so all 16
// q-blocks of a head (and 8 whole heads) land on one XCD -> K/Vt L2-resident.
// S^T = K(A) @ Q^T(B): C-layout puts col=l16=qrow, so each lane's 16 exp2'd
// scores (keys quad*4+r per subtile) form PV A-frags directly under the key
// permutation sigma(q*8+j) = st*32 + (j>>2)*16 + q*4 + (j&3); V B-frags use
// the same sigma (two contiguous b64 chunks from the Vt tile). No P in LDS.
// Occupancy: LDS 36.9KB -> 4 blocks/CU (147.5/160 KB); VGPR free (~110).
__global__ __launch_bounds__(256, 2) void attn_kernel(const unsigned short* __restrict__ Q,
                                                      const unsigned short* __restrict__ K,
                                                      const unsigned short* __restrict__ Vt,
                                                      unsigned short* __restrict__ ctx) {
  const int tid = threadIdx.x;
  const int wave = tid >> 6, lane = tid & 63, quad = lane >> 4, l16 = lane & 15;

  const int id = blockIdx.x;
  const int bh = (id & 7) * 8 + ((id >> 3) >> 4);  // 8 heads per XCD
  const int qx = (id >> 3) & 15;

  // stride 72 ushorts = 36 dwords == 4 mod 32 -> conflict-free-ish frag reads
  // double buffer: [buf][Ks 64*72 | Vts 64*72]
  __shared__ unsigned short sm[2][2 * 64 * 72];

  const size_t hb = (size_t)bh * 131072;
  const int q0 = qx * 128 + wave * 32;

  // Q B-frags: B[k=hd][n=qrow]: lane l16 = qrow, k = quad*8+j (+32*st)
  bf16x8 qf[2][2];
#pragma unroll
  for (int qt = 0; qt < 2; ++qt)
#pragma unroll
    for (int st = 0; st < 2; ++st)
      qf[qt][st] = *(const bf16x8*)(Q + hb + (size_t)(q0 + qt * 16 + l16) * 64 + st * 32 + quad * 8);

  f32x4 o[2][4] = {};
  float lacc[2] = {0.f, 0.f};

  // staging: 4 x 16B chunks/thread (2 K rows-of-keys + 2 Vt rows-of-hd)
  const int c0 = tid, c1 = tid + 256;
  const unsigned short* gK0 = K + hb + (size_t)(c0 >> 3) * 64 + (c0 & 7) * 8;
  const unsigned short* gK1 = K + hb + (size_t)(c1 >> 3) * 64 + (c1 & 7) * 8;
  const unsigned short* gV0 = Vt + hb + (size_t)(c0 >> 3) * 2048 + (c0 & 7) * 8;
  const unsigned short* gV1 = Vt + hb + (size_t)(c1 >> 3) * 2048 + (c1 & 7) * 8;
  const int sKo = (c0 >> 3) * 72 + (c0 & 7) * 8;
  const int sKo1 = (c1 >> 3) * 72 + (c1 & 7) * 8;

  u32x4 pk0 = *(const u32x4*)gK0, pk1 = *(const u32x4*)gK1;
  u32x4 pv0 = *(const u32x4*)gV0, pv1 = *(const u32x4*)gV1;
  {
    unsigned short* s0b = sm[0];
    *(u32x4*)(s0b + sKo) = pk0; *(u32x4*)(s0b + sKo1) = pk1;
    *(u32x4*)(s0b + 4608 + sKo) = pv0; *(u32x4*)(s0b + 4608 + sKo1) = pv1;
  }
  __syncthreads();

  for (int kb = 0; kb < 2048; kb += 64) {
    const int cur = (kb >> 6) & 1;
    const bool more = (kb + 64) < 2048;
    if (more) {
      pk0 = *(const u32x4*)(gK0 + (size_t)(kb + 64) * 64);
      pk1 = *(const u32x4*)(gK1 + (size_t)(kb + 64) * 64);
      pv0 = *(const u32x4*)(gV0 + kb + 64);
      pv1 = *(const u32x4*)(gV1 + kb + 64);
    }
    const unsigned short* Ks = sm[cur];
    const unsigned short* Vts = sm[cur] + 4608;

    // K A-frags: A[m=key][k=hd]: lane l16 = key (per subtile ks), contiguous hd
    bf16x8 kf[4][2];
#pragma unroll
    for (int ks = 0; ks < 4; ++ks)
#pragma unroll
      for (int st = 0; st < 2; ++st)
        kf[ks][st] = *(const bf16x8*)(Ks + (ks * 16 + l16) * 72 + st * 32 + quad * 8);

    // V B-frags under sigma: two b64 chunks (keys st*32+quad*4+{0..3}, +16)
    bf16x8 vf[4][2];
#pragma unroll
    for (int os = 0; os < 4; ++os)
#pragma unroll
      for (int st = 0; st < 2; ++st) {
        const unsigned short* rb = Vts + (os * 16 + l16) * 72 + st * 32 + quad * 4;
        bf16x4 a = *(const bf16x4*)rb;
        bf16x4 b2 = *(const bf16x4*)(rb + 16);
        vf[os][st] = __builtin_shufflevector(a, b2, 0, 1, 2, 3, 4, 5, 6, 7);
      }

#pragma unroll
    for (int qt = 0; qt < 2; ++qt) {
      // S^T tiles: rows = keys (quad*4+r), cols = qrows (l16)
      f32x4 sc[4];
      __builtin_amdgcn_s_setprio(1);
#pragma unroll
      for (int ks = 0; ks < 4; ++ks) {
        f32x4 a = {0.f, 0.f, 0.f, 0.f};
        a = MFMA16(kf[ks][0], qf[qt][0], a);
        a = MFMA16(kf[ks][1], qf[qt][1], a);
        sc[ks] = a;
      }
      __builtin_amdgcn_s_setprio(0);
      // exp2 -> P A-frags in-register; per-lane l partials (all for qrow l16)
      bf16x8 pf[2];
      float ls = 0.f;
#pragma unroll
      for (int ks = 0; ks < 4; ++ks)
#pragma unroll
        for (int r = 0; r < 4; ++r) {
          float p = __builtin_amdgcn_exp2f(sc[ks][r]);
          ls += p;
          pf[ks >> 1][(ks & 1) * 4 + r] = (__bf16)p;
        }
      lacc[qt] += ls;
      __builtin_amdgcn_s_setprio(1);
#pragma unroll
      for (int st = 0; st < 2; ++st)
#pragma unroll
        for (int os = 0; os < 4; ++os)
          o[qt][os] = MFMA16(pf[st], vf[os][st], o[qt][os]);
      __builtin_amdgcn_s_setprio(0);
    }

    if (more) {
      unsigned short* sn = sm[cur ^ 1];
      *(u32x4*)(sn + sKo) = pk0; *(u32x4*)(sn + sKo1) = pk1;
      *(u32x4*)(sn + 4608 + sKo) = pv0; *(u32x4*)(sn + 4608 + sKo1) = pv1;
    }
    __syncthreads();
  }

  // finalize: reduce l across quads (lane's l16 = qrow), redistribute to
  // C-layout rows (quad*4+r), normalize, store.
  const int b = bh >> 4, h = bh & 15;
#pragma unroll
  for (int qt = 0; qt < 2; ++qt) {
    float l = lacc[qt];
    l += __shfl_xor(l, 16, 64);
    l += __shfl_xor(l, 32, 64);
#pragma unroll
    for (int r = 0; r < 4; ++r) {
      float lr = __shfl(l, quad * 4 + r, 16);
      float inv = 1.0f / lr;
      int s = q0 + qt * 16 + quad * 4 + r;
#pragma unroll
      for (int os = 0; os < 4; ++os)
        ctx[((size_t)(b * 2048 + s)) * 1024 + h * 64 + os * 16 + l16] = f2bf(o[qt][os][r] * inv);
    }
  }
}

// ---------------------------------------------------------------- launch
extern "C" void kernel_launch(void* const* d_in, const int* in_sizes, int n_in,
                              void* d_out, int out_size, void* d_ws, size_t ws_size,
                              hipStream_t stream) {
  const float* x  = (const float*)d_in[0];
  const float* Wq = (const float*)d_in[1];
  const float* bq = (const float*)d_in[2];
  const float* Wk = (const float*)d_in[3];
  const float* bk = (const float*)d_in[4];
  const float* Wv = (const float*)d_in[5];
  const float* bv = (const float*)d_in[6];
  const float* Wo = (const float*)d_in[7];
  const float* bo = (const float*)d_in[8];

  unsigned short* ws = (unsigned short*)d_ws;
  unsigned short* xb    = ws;                    // 8388608 (aliased by VtG later)
  unsigned short* Wtall = ws + 8388608;          // 4*1048576 (Wq^T|Wk^T|Wv^T|Wo^T)
  unsigned short* Wot   = Wtall + 3145728;
  unsigned short* Qb    = Wtall + 4194304;       // 8388608  [bh][s][hd], pre-scaled
  unsigned short* Kb    = Qb + 8388608;          // 8388608
  unsigned short* Vb    = Kb + 8388608;          // 8388608
  unsigned short* VtG   = xb;                    // alias: xb dead after QKV GEMM
  unsigned short* Cb    = Vb;                    // alias: Vb dead after transpose_v

  cast_x_kernel<<<8192, 256, 0, stream>>>(x, xb, 2097152);
  transpose_cast4<<<dim3(32, 32, 4), dim3(32, 8), 0, stream>>>(Wq, Wk, Wv, Wo, Wtall);

  gemm128<1><<<dim3(24, 64), 256, 0, stream>>>(xb, Wtall, bq, bk, bv, Qb);
  transpose_v<<<dim3(32, 64), 256, 0, stream>>>(Vb, VtG);
  attn_kernel<<<dim3(1024), 256, 0, stream>>>(Qb, Kb, VtG, Cb);
  gemm128<0><<<dim3(8, 64), 256, 0, stream>>>(Cb, Wot, bo, nullptr, nullptr, d_out);
}

// Round 3
// 272.869 us; speedup vs baseline: 2.3050x; 1.0748x over previous
//
#include <hip/hip_runtime.h>
#include <stdint.h>

// B=4, S=2048, D=1024, H=16, Hd=64, M=8192.
// Pipeline: cast x -> bf16; merged W^T casts; merged QKV GEMM (Q pre-scaled
// by log2e/8); V transpose to [bh][hd][s]; flash attn computing S^T = K@Q^T
// so exp2(scores) form PV A-frags in-register (key-permutation trick, no P
// LDS round-trip); O-projection GEMM (fp32 out).
// R1: q-split 1024 blocks + XCD decode + setprio -> spilled (launch_bounds(,4)).
// R2: (,2) fixed spill; proved XCD decode cuts FETCH 139->24.6 MB, but q-split
//     doubled LDS read traffic (conflicts 6.3M->12.6M) -> 98 us. Per-wave
//     q-count amortizes LDS reads; revert split.
// R3: attn back to R0 geometry (512 blk x 4 waves x 64 q-rows) KEEPING the
//     XCD-grouped head decode + setprio. GEMMs get XCD-chunked 2D swizzle:
//     XCD owns 8 output row-panels (A 2MB L2-resident, reused 24x/8x),
//     bx-major by-inner order within XCD.

typedef float f32x4 __attribute__((ext_vector_type(4)));
typedef __bf16 bf16x4 __attribute__((ext_vector_type(4)));
typedef __bf16 bf16x8 __attribute__((ext_vector_type(8)));
typedef uint32_t u32x4 __attribute__((ext_vector_type(4)));

#define MFMA16(a, b, c) __builtin_amdgcn_mfma_f32_16x16x32_bf16((a), (b), (c), 0, 0, 0)

// Q pre-scale: log2(e)/8 so attn does p = exp2(Q'.K) = e^{QK/8} (unnormalized)
#define QSCALE 0.1803368801111204f

__device__ __forceinline__ unsigned short f2bf(float f) {
  union { float f; uint32_t u; } c; c.f = f;
  uint32_t u = c.u;
  return (unsigned short)((u + 0x7fffu + ((u >> 16) & 1u)) >> 16);  // RNE
}

// ---------------------------------------------------------------- casts
__global__ __launch_bounds__(256) void cast_x_kernel(const float* __restrict__ in,
                                                     unsigned short* __restrict__ out,
                                                     int n4) {
  int i = blockIdx.x * 256 + threadIdx.x;
  if (i >= n4) return;
  float4 v = ((const float4*)in)[i];
  ushort4 o;
  o.x = f2bf(v.x); o.y = f2bf(v.y); o.z = f2bf(v.z); o.w = f2bf(v.w);
  ((ushort4*)out)[i] = o;
}

// 4 weights [k][n] fp32 -> Wt [n][k] bf16, z selects matrix; dst contiguous.
__global__ __launch_bounds__(256) void transpose_cast4(const float* __restrict__ W0,
                                                       const float* __restrict__ W1,
                                                       const float* __restrict__ W2,
                                                       const float* __restrict__ W3,
                                                       unsigned short* __restrict__ Wt) {
  __shared__ float tile[32][33];
  const int z = blockIdx.z;
  const float* W = (z == 0) ? W0 : (z == 1) ? W1 : (z == 2) ? W2 : W3;
  unsigned short* dst = Wt + (size_t)z * 1048576;
  int k0 = blockIdx.x * 32, n0 = blockIdx.y * 32;
  int tx = threadIdx.x, ty = threadIdx.y;
#pragma unroll
  for (int i = 0; i < 32; i += 8)
    tile[ty + i][tx] = W[(size_t)(k0 + ty + i) * 1024 + n0 + tx];
  __syncthreads();
#pragma unroll
  for (int i = 0; i < 32; i += 8)
    dst[(size_t)(n0 + ty + i) * 1024 + k0 + tx] = f2bf(tile[tx][ty + i]);
}

// ---------------------------------------------------------------- GEMM
// MODE 0: O-proj. out fp32 [8192][1024], bias b0. grid 512 flat.
// MODE 1: merged QKV. Bt = [3072][1024], out = QKV bf16 base (3 x 8388608),
//         scatter to [b,h,s,hd]; Q (mb==0) scaled by QSCALE. grid 1536 flat.
// XCD-chunked decode: XCD x owns by in [8x, 8x+8); within XCD bx-major,
// by-inner -> 8 A-panels (2MB) L2-resident, B-panel reused 8x per visit.
template <int MODE>
__global__ __launch_bounds__(256) void gemm128(const unsigned short* __restrict__ A,
                                               const unsigned short* __restrict__ Bt,
                                               const float* __restrict__ b0,
                                               const float* __restrict__ b1,
                                               const float* __restrict__ b2,
                                               void* __restrict__ out) {
  constexpr int Kd = 1024;
  __shared__ unsigned short sm[128 * 32 + 32 * 128];
  unsigned short* As = sm;
  unsigned short* Bs = sm + 128 * 32;
  auto lds3 = (__attribute__((address_space(3))) char*)sm;

  const int tid = threadIdx.x;
  const int wave = tid >> 6, lane = tid & 63, quad = lane >> 4, l16 = lane & 15;
  const int wm = wave >> 1, wn = wave & 1;

  const int id = blockIdx.x;
  const int nid = id >> 3;
  const int by = (id & 7) * 8 + (nid & 7);
  const int bx = nid >> 3;
  const int bm = by * 128, bn = bx * 128;

  f32x4 acc[4][4] = {};

  for (int k0 = 0; k0 < Kd; k0 += 32) {
#pragma unroll
    for (int j = 0; j < 2; ++j) {
      int i = (wave * 2 + j) * 64 + lane;  // 16B-chunk index 0..511
      const unsigned short* ga = A + (size_t)(bm + (i >> 2)) * Kd + k0 + (i & 3) * 8;
      __builtin_amdgcn_global_load_lds(
          (const __attribute__((address_space(1))) void*)ga,
          (__attribute__((address_space(3))) void*)(lds3 + (size_t)(wave * 2 + j) * 1024),
          16, 0, 0);
      const unsigned short* gb = Bt + (size_t)(bn + (i >> 2)) * Kd + k0 + (i & 3) * 8;
      __builtin_amdgcn_global_load_lds(
          (const __attribute__((address_space(1))) void*)gb,
          (__attribute__((address_space(3))) void*)(lds3 + 8192 + (size_t)(wave * 2 + j) * 1024),
          16, 0, 0);
    }
    __syncthreads();

    bf16x8 af[4], bfv[4];
#pragma unroll
    for (int i = 0; i < 4; ++i)
      af[i] = *(const bf16x8*)(As + (wm * 64 + i * 16 + l16) * 32 + quad * 8);
#pragma unroll
    for (int n = 0; n < 4; ++n)
      bfv[n] = *(const bf16x8*)(Bs + (wn * 64 + n * 16 + l16) * 32 + quad * 8);
#pragma unroll
    for (int i = 0; i < 4; ++i)
#pragma unroll
      for (int n = 0; n < 4; ++n)
        acc[i][n] = MFMA16(af[i], bfv[n], acc[i][n]);
    __syncthreads();
  }

  // epilogue: C/D layout col=lane&15, row=quad*4+reg
  const int mb = bn >> 10;  // matrix id for MODE 1 (block never straddles: 1024%128==0)
  const float* bias = (MODE == 0) ? b0 : (mb == 0 ? b0 : (mb == 1 ? b1 : b2));
  const float scale = (MODE == 1 && mb == 0) ? QSCALE : 1.0f;
  unsigned short* oq = (MODE == 1) ? ((unsigned short*)out + (size_t)mb * 8388608u) : nullptr;

#pragma unroll
  for (int i = 0; i < 4; ++i) {
    const int row0 = bm + wm * 64 + i * 16 + quad * 4;
#pragma unroll
    for (int n = 0; n < 4; ++n) {
      const int col = bn + wn * 64 + n * 16 + l16;
      const int cl = col & 1023;
      const float bv = bias[cl];
#pragma unroll
      for (int r = 0; r < 4; ++r) {
        float v = (acc[i][n][r] + bv) * scale;
        if (MODE == 0) {
          ((float*)out)[(size_t)(row0 + r) * 1024 + col] = v;
        } else {
          int rr = row0 + r;
          int b = rr >> 11, s = rr & 2047;
          int h = cl >> 6, hd = cl & 63;
          oq[((size_t)(b * 16 + h) * 2048 + s) * 64 + hd] = f2bf(v);
        }
      }
    }
  }
}

// ---------------------------------------------------------------- V transpose
// Vb [bh][s][64] bf16 -> VtG [bh][64][2048] bf16.
__global__ __launch_bounds__(256) void transpose_v(const unsigned short* __restrict__ Vb,
                                                   unsigned short* __restrict__ VtG) {
  __shared__ uint32_t t32[64][33];
  const int bh = blockIdx.y, s0 = blockIdx.x * 64;
  const int tid = threadIdx.x;
  const size_t hbase = (size_t)bh * 131072;
#pragma unroll
  for (int it = 0; it < 2; ++it) {
    int c = tid + it * 256;
    int sr = c >> 3, o4 = (c & 7) * 4;
    u32x4 v = *(const u32x4*)(Vb + hbase + (size_t)(s0 + sr) * 64 + o4 * 2);
    t32[sr][o4] = v[0]; t32[sr][o4 + 1] = v[1];
    t32[sr][o4 + 2] = v[2]; t32[sr][o4 + 3] = v[3];
  }
  __syncthreads();
#pragma unroll
  for (int it = 0; it < 2; ++it) {
    int c = tid + it * 256;
    int hd = c >> 3, so = (c & 7) * 8;
    int hc = hd >> 1, sh = (hd & 1) * 16;
    uint32_t w[4];
#pragma unroll
    for (int j = 0; j < 4; ++j) {
      uint32_t lo = t32[so + 2 * j][hc], hi = t32[so + 2 * j + 1][hc];
      w[j] = ((lo >> sh) & 0xffffu) | (((hi >> sh) & 0xffffu) << 16);
    }
    *(u32x4*)(VtG + hbase + (size_t)hd * 2048 + s0 + so) = *(u32x4*)w;
  }
}

// ---------------------------------------------------------------- flash attention
// Q pre-scaled. 512 flat blocks; block = (b,h) x 256 q-rows; wave = 64 q-rows
// (4 subtiles). XCD-grouped decode: bh = (id&7)*8 + ((id>>3)>>3) so all 8
// q-blocks of a head (and 8 whole heads) land on one XCD -> K/Vt L2-resident
// (proven R2: FETCH 139 -> 24.6 MB).
// S^T = K(A) @ Q^T(B): C-layout puts col=l16=qrow, so each lane's 16 exp2'd
// scores (keys quad*4+r per subtile) form PV A-frags directly under the key
// permutation sigma(q*8+j) = st*32 + (j>>2)*16 + q*4 + (j&3); V B-frags use
// the same sigma (two contiguous b64 chunks from the Vt tile). No P in LDS.
__global__ __launch_bounds__(256, 2) void attn_kernel(const unsigned short* __restrict__ Q,
                                                      const unsigned short* __restrict__ K,
                                                      const unsigned short* __restrict__ Vt,
                                                      unsigned short* __restrict__ ctx) {
  const int tid = threadIdx.x;
  const int wave = tid >> 6, lane = tid & 63, quad = lane >> 4, l16 = lane & 15;

  const int id = blockIdx.x;
  const int bh = (id & 7) * 8 + ((id >> 3) >> 3);  // 8 heads per XCD
  const int qx = (id >> 3) & 7;

  // stride 72 ushorts = 36 dwords == 4 mod 32 -> conflict-free-ish frag reads
  // double buffer: [buf][Ks 64*72 | Vts 64*72]
  __shared__ unsigned short sm[2][2 * 64 * 72];

  const size_t hb = (size_t)bh * 131072;
  const int q0 = qx * 256 + wave * 64;

  // Q B-frags: B[k=hd][n=qrow]: lane l16 = qrow, k = quad*8+j (+32*st)
  bf16x8 qf[4][2];
#pragma unroll
  for (int qt = 0; qt < 4; ++qt)
#pragma unroll
    for (int st = 0; st < 2; ++st)
      qf[qt][st] = *(const bf16x8*)(Q + hb + (size_t)(q0 + qt * 16 + l16) * 64 + st * 32 + quad * 8);

  f32x4 o[4][4] = {};
  float lacc[4] = {0.f, 0.f, 0.f, 0.f};

  // staging: 4 x 16B chunks/thread (2 K rows-of-keys + 2 Vt rows-of-hd)
  const int c0 = tid, c1 = tid + 256;
  const unsigned short* gK0 = K + hb + (size_t)(c0 >> 3) * 64 + (c0 & 7) * 8;
  const unsigned short* gK1 = K + hb + (size_t)(c1 >> 3) * 64 + (c1 & 7) * 8;
  const unsigned short* gV0 = Vt + hb + (size_t)(c0 >> 3) * 2048 + (c0 & 7) * 8;
  const unsigned short* gV1 = Vt + hb + (size_t)(c1 >> 3) * 2048 + (c1 & 7) * 8;
  const int sKo = (c0 >> 3) * 72 + (c0 & 7) * 8;
  const int sKo1 = (c1 >> 3) * 72 + (c1 & 7) * 8;

  u32x4 pk0 = *(const u32x4*)gK0, pk1 = *(const u32x4*)gK1;
  u32x4 pv0 = *(const u32x4*)gV0, pv1 = *(const u32x4*)gV1;
  {
    unsigned short* s0b = sm[0];
    *(u32x4*)(s0b + sKo) = pk0; *(u32x4*)(s0b + sKo1) = pk1;
    *(u32x4*)(s0b + 4608 + sKo) = pv0; *(u32x4*)(s0b + 4608 + sKo1) = pv1;
  }
  __syncthreads();

  for (int kb = 0; kb < 2048; kb += 64) {
    const int cur = (kb >> 6) & 1;
    const bool more = (kb + 64) < 2048;
    if (more) {
      pk0 = *(const u32x4*)(gK0 + (size_t)(kb + 64) * 64);
      pk1 = *(const u32x4*)(gK1 + (size_t)(kb + 64) * 64);
      pv0 = *(const u32x4*)(gV0 + kb + 64);
      pv1 = *(const u32x4*)(gV1 + kb + 64);
    }
    const unsigned short* Ks = sm[cur];
    const unsigned short* Vts = sm[cur] + 4608;

    // K A-frags: A[m=key][k=hd]: lane l16 = key (per subtile ks), contiguous hd
    bf16x8 kf[4][2];
#pragma unroll
    for (int ks = 0; ks < 4; ++ks)
#pragma unroll
      for (int st = 0; st < 2; ++st)
        kf[ks][st] = *(const bf16x8*)(Ks + (ks * 16 + l16) * 72 + st * 32 + quad * 8);

    // V B-frags under sigma: two b64 chunks (keys st*32+quad*4+{0..3}, +16)
    bf16x8 vf[4][2];
#pragma unroll
    for (int os = 0; os < 4; ++os)
#pragma unroll
      for (int st = 0; st < 2; ++st) {
        const unsigned short* rb = Vts + (os * 16 + l16) * 72 + st * 32 + quad * 4;
        bf16x4 a = *(const bf16x4*)rb;
        bf16x4 b2 = *(const bf16x4*)(rb + 16);
        vf[os][st] = __builtin_shufflevector(a, b2, 0, 1, 2, 3, 4, 5, 6, 7);
      }

#pragma unroll
    for (int qt = 0; qt < 4; ++qt) {
      // S^T tiles: rows = keys (quad*4+r), cols = qrows (l16)
      f32x4 sc[4];
      __builtin_amdgcn_s_setprio(1);
#pragma unroll
      for (int ks = 0; ks < 4; ++ks) {
        f32x4 a = {0.f, 0.f, 0.f, 0.f};
        a = MFMA16(kf[ks][0], qf[qt][0], a);
        a = MFMA16(kf[ks][1], qf[qt][1], a);
        sc[ks] = a;
      }
      __builtin_amdgcn_s_setprio(0);
      // exp2 -> P A-frags in-register; per-lane l partials (all for qrow l16)
      bf16x8 pf[2];
      float ls = 0.f;
#pragma unroll
      for (int ks = 0; ks < 4; ++ks)
#pragma unroll
        for (int r = 0; r < 4; ++r) {
          float p = __builtin_amdgcn_exp2f(sc[ks][r]);
          ls += p;
          pf[ks >> 1][(ks & 1) * 4 + r] = (__bf16)p;
        }
      lacc[qt] += ls;
      __builtin_amdgcn_s_setprio(1);
#pragma unroll
      for (int st = 0; st < 2; ++st)
#pragma unroll
        for (int os = 0; os < 4; ++os)
          o[qt][os] = MFMA16(pf[st], vf[os][st], o[qt][os]);
      __builtin_amdgcn_s_setprio(0);
    }

    if (more) {
      unsigned short* sn = sm[cur ^ 1];
      *(u32x4*)(sn + sKo) = pk0; *(u32x4*)(sn + sKo1) = pk1;
      *(u32x4*)(sn + 4608 + sKo) = pv0; *(u32x4*)(sn + 4608 + sKo1) = pv1;
    }
    __syncthreads();
  }

  // finalize: reduce l across quads (lane's l16 = qrow), redistribute to
  // C-layout rows (quad*4+r), normalize, store.
  const int b = bh >> 4, h = bh & 15;
#pragma unroll
  for (int qt = 0; qt < 4; ++qt) {
    float l = lacc[qt];
    l += __shfl_xor(l, 16, 64);
    l += __shfl_xor(l, 32, 64);
#pragma unroll
    for (int r = 0; r < 4; ++r) {
      float lr = __shfl(l, quad * 4 + r, 16);
      float inv = 1.0f / lr;
      int s = q0 + qt * 16 + quad * 4 + r;
#pragma unroll
      for (int os = 0; os < 4; ++os)
        ctx[((size_t)(b * 2048 + s)) * 1024 + h * 64 + os * 16 + l16] = f2bf(o[qt][os][r] * inv);
    }
  }
}

// ---------------------------------------------------------------- launch
extern "C" void kernel_launch(void* const* d_in, const int* in_sizes, int n_in,
                              void* d_out, int out_size, void* d_ws, size_t ws_size,
                              hipStream_t stream) {
  const float* x  = (const float*)d_in[0];
  const float* Wq = (const float*)d_in[1];
  const float* bq = (const float*)d_in[2];
  const float* Wk = (const float*)d_in[3];
  const float* bk = (const float*)d_in[4];
  const float* Wv = (const float*)d_in[5];
  const float* bv = (const float*)d_in[6];
  const float* Wo = (const float*)d_in[7];
  const float* bo = (const float*)d_in[8];

  unsigned short* ws = (unsigned short*)d_ws;
  unsigned short* xb    = ws;                    // 8388608 (aliased by VtG later)
  unsigned short* Wtall = ws + 8388608;          // 4*1048576 (Wq^T|Wk^T|Wv^T|Wo^T)
  unsigned short* Wot   = Wtall + 3145728;
  unsigned short* Qb    = Wtall + 4194304;       // 8388608  [bh][s][hd], pre-scaled
  unsigned short* Kb    = Qb + 8388608;          // 8388608
  unsigned short* Vb    = Kb + 8388608;          // 8388608
  unsigned short* VtG   = xb;                    // alias: xb dead after QKV GEMM
  unsigned short* Cb    = Vb;                    // alias: Vb dead after transpose_v

  cast_x_kernel<<<8192, 256, 0, stream>>>(x, xb, 2097152);
  transpose_cast4<<<dim3(32, 32, 4), dim3(32, 8), 0, stream>>>(Wq, Wk, Wv, Wo, Wtall);

  gemm128<1><<<dim3(1536), 256, 0, stream>>>(xb, Wtall, bq, bk, bv, Qb);
  transpose_v<<<dim3(32, 64), 256, 0, stream>>>(Vb, VtG);
  attn_kernel<<<dim3(512), 256, 0, stream>>>(Qb, Kb, VtG, Cb);
  gemm128<0><<<dim3(512), 256, 0, stream>>>(Cb, Wot, bo, nullptr, nullptr, d_out);
}